// Round 3
// baseline (273.947 us; speedup 1.0000x reference)
//
#include <hip/hip_runtime.h>

// CARAFE restructured: z = Wo*x at LOW res, fused reassembly+shuffle+bias.
// R3: k_down / k_enc rebuilt as register-blocked direct convs:
//   - o-chunk per thread (8 / 10) so each staged activation feeds many FMAs
//   - contiguous per-o weight rows -> batched s_load_dwordx16 (was strided dword)
//   - manual double-buffered activation prefetch to hide L1/L2 latency
// N=4, H=W=64, INC=256, CM=64, KUP=5, DELTA=2, enc_out=100, OUTC=256.

namespace {
constexpr int kN = 4, kH = 64, kW = 64, kINC = 256, kCM = 64;
constexpr int kENC = 100, kH2 = 128, kW2 = 128, kOUTC = 256;
constexpr int kHW = kH * kW;       // 4096
constexpr int kHW2 = kH2 * kW2;    // 16384
}

// ---------- kernel 1: 1x1 down conv: x(N,256,64,64) -> down(N,64,64,64) ----------
// 2048 single-wave blocks: h(64) x og(8) x n(4). Thread: 1 pixel, 8 out chans.
// K=256 in sub-chunks of 8, double-buffered; weights = contiguous scalar rows.
__global__ __launch_bounds__(64) void k_down(
    const float* __restrict__ x, const float* __restrict__ wd,
    const float* __restrict__ bd, float* __restrict__ down) {
  const int b = blockIdx.x;
  const int h = b & 63, og = (b >> 6) & 7, n = b >> 9;
  const int w = threadIdx.x;
  const int o0 = og << 3;
  const int pix = h * kW + w;
  const float* xb = x + (size_t)n * kINC * kHW + pix;

  float acc[8];
#pragma unroll
  for (int i = 0; i < 8; ++i) acc[i] = bd[o0 + i];

  float va[8], vb[8];
#pragma unroll
  for (int c = 0; c < 8; ++c) va[c] = xb[(size_t)c * kHW];

  for (int cc = 0; cc < kINC; cc += 16) {
#pragma unroll
    for (int c = 0; c < 8; ++c) vb[c] = xb[(size_t)(cc + 8 + c) * kHW];
#pragma unroll
    for (int o = 0; o < 8; ++o) {
      const float* wr = wd + (size_t)(o0 + o) * kINC + cc;
#pragma unroll
      for (int c = 0; c < 8; ++c) acc[o] += wr[c] * va[c];
    }
    const int nxt = (cc + 16 < kINC) ? cc + 16 : 0;
#pragma unroll
    for (int c = 0; c < 8; ++c) va[c] = xb[(size_t)(nxt + c) * kHW];
#pragma unroll
    for (int o = 0; o < 8; ++o) {
      const float* wr = wd + (size_t)(o0 + o) * kINC + cc + 8;
#pragma unroll
      for (int c = 0; c < 8; ++c) acc[o] += wr[c] * vb[c];
    }
  }
  float* ob = down + (size_t)(n * kCM + o0) * kHW + pix;
#pragma unroll
  for (int o = 0; o < 8; ++o) ob[(size_t)o * kHW] = acc[o];
}

// ---------- kernel 2: 3x3 enc conv: down(N,64,64,64) -> enc(N,100,64,64) ----------
// 2560 single-wave blocks: h(64) x og(10) x n(4). Thread: 1 pixel, 10 out chans.
// Sub-chunk = 4 ci x 9 taps = 36 activations (double-buffered); the matching
// 36 weights per o are CONTIGUOUS (ci*9+tap) -> s_load_dwordx16 batches.
__global__ __launch_bounds__(64) void k_enc(
    const float* __restrict__ down, const float* __restrict__ we,
    const float* __restrict__ be, float* __restrict__ enc) {
  const int b = blockIdx.x;
  const int h = b & 63;
  const int t0 = b >> 6;
  const int og = t0 % 10, n = t0 / 10;
  const int w = threadIdx.x;
  const int o0 = og * 10;
  const int pix = h * kW + w;
  const float* db = down + (size_t)n * kCM * kHW;

  // 9 tap offsets relative to pix, clamped to a safe address; ok[] = validity
  int idx[9];
  bool ok[9];
#pragma unroll
  for (int kh = 0; kh < 3; ++kh) {
#pragma unroll
    for (int kw = 0; kw < 3; ++kw) {
      const int hh = h + kh - 1, ww = w + kw - 1;
      const bool v = (hh >= 0) & (hh < kH) & (ww >= 0) & (ww < kW);
      ok[kh * 3 + kw] = v;
      idx[kh * 3 + kw] = v ? (hh * kW + ww) : pix;   // clamped: always in-bounds
    }
  }

  float acc[10];
#pragma unroll
  for (int i = 0; i < 10; ++i) acc[i] = be[o0 + i];

  float va[36], vb[36];
#define LOAD36(V, CI0)                                            \
  {                                                               \
    const int ci_ = (CI0);                                        \
    _Pragma("unroll") for (int c = 0; c < 4; ++c) {               \
      _Pragma("unroll") for (int t = 0; t < 9; ++t) {             \
        const float x_ = db[(size_t)(ci_ + c) * kHW + idx[t]];    \
        (V)[c * 9 + t] = ok[t] ? x_ : 0.f;                        \
      }                                                           \
    }                                                             \
  }
#define FMA36(V, CI0)                                             \
  {                                                               \
    const int cb_ = (CI0) * 9;                                    \
    _Pragma("unroll") for (int o = 0; o < 10; ++o) {              \
      const float* wr_ = we + (size_t)(o0 + o) * 576 + cb_;       \
      _Pragma("unroll") for (int t = 0; t < 36; ++t)              \
          acc[o] += wr_[t] * (V)[t];                              \
    }                                                             \
  }

  LOAD36(va, 0);
  for (int cc = 0; cc < kCM; cc += 8) {
    LOAD36(vb, cc + 4);
    FMA36(va, cc);
    const int nxt = (cc + 8 < kCM) ? cc + 8 : 0;
    LOAD36(va, nxt);
    FMA36(vb, cc + 4);
  }
#undef LOAD36
#undef FMA36

  float* ob = enc + (size_t)(n * kENC + o0) * kHW + pix;
#pragma unroll
  for (int o = 0; o < 10; ++o) ob[(size_t)o * kHW] = acc[o];
}

// ---------- kernel 3: softmax over the 25 kernel taps, in place ----------
__global__ __launch_bounds__(256) void k_softmax(float* __restrict__ buf) {
  const int b = blockIdx.x;                 // 256 blocks: hg(16) x d(4) x n(4)
  const int hg = b & 15, d = (b >> 4) & 3, n = b >> 6;
  const int tid = threadIdx.x;
  const int h = (hg << 2) + (tid >> 6), w = tid & 63;
  float* base = buf + ((size_t)n * kENC + d) * kHW + h * kW + w;
  float v[25];
  float m = -1e30f;
#pragma unroll
  for (int k = 0; k < 25; ++k) { v[k] = base[(size_t)k * 4 * kHW]; m = fmaxf(m, v[k]); }
  float s = 0.f;
#pragma unroll
  for (int k = 0; k < 25; ++k) { v[k] = __expf(v[k] - m); s += v[k]; }
  const float inv = 1.f / s;
#pragma unroll
  for (int k = 0; k < 25; ++k) base[(size_t)k * 4 * kHW] = v[k] * inv;
}

// ---------- kernel 4: z = Wo * x (1x1, 256->256 at 64x64 res), no bias ----------
__global__ __launch_bounds__(256) void k_zgemm(
    const float* __restrict__ x, const float* __restrict__ wo,
    float* __restrict__ z) {
  const int b = blockIdx.x;                 // 1024 blocks: pT(64) x oT(4) x n(4)
  const int pT = b & 63, oT = (b >> 6) & 3, n = b >> 8;
  const int p0 = pT << 6, o0 = oT << 6;
  const int tid = threadIdx.x;
  const int tx = tid & 15, ty = tid >> 4;
  __shared__ float As[16][64];              // [k][o]
  __shared__ float Bs[16][64];              // [k][p]
  const float* Ab = wo + (size_t)o0 * kINC;
  const float* Bb = x + (size_t)n * kINC * kHW + p0;
  float acc[4][4] = {};
  const int ar = tid >> 2, ac = (tid & 3) << 2;
  const int br = tid >> 4, bc = (tid & 15) << 2;
  for (int k0 = 0; k0 < kINC; k0 += 16) {
    const float4 av = *(const float4*)(Ab + (size_t)ar * kINC + k0 + ac);
    As[ac + 0][ar] = av.x; As[ac + 1][ar] = av.y;
    As[ac + 2][ar] = av.z; As[ac + 3][ar] = av.w;
    const float4 bv = *(const float4*)(Bb + (size_t)(k0 + br) * kHW + bc);
    *(float4*)(&Bs[br][bc]) = bv;
    __syncthreads();
#pragma unroll
    for (int kk = 0; kk < 16; ++kk) {
      const float a0 = As[kk][ty * 4 + 0], a1 = As[kk][ty * 4 + 1];
      const float a2 = As[kk][ty * 4 + 2], a3 = As[kk][ty * 4 + 3];
      const float b0 = Bs[kk][tx * 4 + 0], b1 = Bs[kk][tx * 4 + 1];
      const float b2 = Bs[kk][tx * 4 + 2], b3 = Bs[kk][tx * 4 + 3];
      acc[0][0] += a0 * b0; acc[0][1] += a0 * b1; acc[0][2] += a0 * b2; acc[0][3] += a0 * b3;
      acc[1][0] += a1 * b0; acc[1][1] += a1 * b1; acc[1][2] += a1 * b2; acc[1][3] += a1 * b3;
      acc[2][0] += a2 * b0; acc[2][1] += a2 * b1; acc[2][2] += a2 * b2; acc[2][3] += a2 * b3;
      acc[3][0] += a3 * b0; acc[3][1] += a3 * b1; acc[3][2] += a3 * b2; acc[3][3] += a3 * b3;
    }
    __syncthreads();
  }
#pragma unroll
  for (int i = 0; i < 4; ++i) {
    const int o = o0 + ty * 4 + i;
    *(float4*)(z + ((size_t)(n * kOUTC + o) * kHW) + p0 + tx * 4) =
        make_float4(acc[i][0], acc[i][1], acc[i][2], acc[i][3]);
  }
}

// ---------- kernel 5: fused reassembly + pixel shuffle + bias -> out ----------
__global__ __launch_bounds__(256) void k_fused_out(
    const float* __restrict__ z, const float* __restrict__ kern,
    const float* __restrict__ bo, float* __restrict__ out) {
  const int b = blockIdx.x;                 // 4096 blocks: hg(16) x og(64) x n(4)
  const int hg = b & 15, og = (b >> 4) & 63, n = b >> 10;
  const int tid = threadIdx.x;
  const int h = (hg << 2) + (tid >> 6), w = tid & 63;
  const int o0 = og << 2;
  const float* kb = kern + (size_t)n * kENC * kHW + h * kW + w;
  const float* zb = z + (size_t)(n * kOUTC + o0) * kHW;
  float acc[4][4] = {};                     // [o][d]
#pragma unroll
  for (int kh = 0; kh < 5; ++kh) {
    const int hh = h + kh - 2;
    if (hh < 0 || hh >= kH) continue;       // wave-uniform
#pragma unroll
    for (int kw = 0; kw < 5; ++kw) {
      const int ww = w + kw - 2;
      if (ww < 0 || ww >= kW) continue;
      const int k = kh * 5 + kw;
      const float kv0 = kb[(size_t)(k * 4    ) * kHW];
      const float kv1 = kb[(size_t)(k * 4 + 1) * kHW];
      const float kv2 = kb[(size_t)(k * 4 + 2) * kHW];
      const float kv3 = kb[(size_t)(k * 4 + 3) * kHW];
      const int xoff = hh * kW + ww;
#pragma unroll
      for (int u = 0; u < 4; ++u) {
        const float zv = zb[(size_t)u * kHW + xoff];
        acc[u][0] += zv * kv0; acc[u][1] += zv * kv1;
        acc[u][2] += zv * kv2; acc[u][3] += zv * kv3;
      }
    }
  }
#pragma unroll
  for (int u = 0; u < 4; ++u) {
    const float bias = bo[o0 + u];
#pragma unroll
    for (int i = 0; i < 2; ++i) {
      float* dst = out + ((size_t)(n * kOUTC + o0 + u) * kH2 + (2 * h + i)) * kW2 + 2 * w;
      *(float2*)dst = make_float2(acc[u][i * 2] + bias, acc[u][i * 2 + 1] + bias);
    }
  }
}

extern "C" void kernel_launch(void* const* d_in, const int* in_sizes, int n_in,
                              void* d_out, int out_size, void* d_ws, size_t ws_size,
                              hipStream_t stream) {
  const float* x  = (const float*)d_in[0];   // (4,256,64,64)
  const float* wd = (const float*)d_in[1];   // (64,256,1,1)
  const float* bd = (const float*)d_in[2];   // (64,)
  const float* we = (const float*)d_in[3];   // (100,64,3,3)
  const float* be = (const float*)d_in[4];   // (100,)
  const float* wo = (const float*)d_in[5];   // (256,256,1,1)
  const float* bo = (const float*)d_in[6];   // (256,)
  float* out = (float*)d_out;                // (4,256,128,128)

  // workspace layout (floats): down | enc (softmaxed in place) | z
  float* down = (float*)d_ws;                // 4*64*4096  = 1,048,576
  float* enc  = down + 1048576;              // 4*100*4096 = 1,638,400
  float* z    = enc + 1638400;               // 4*256*4096 = 4,194,304

  k_down<<<2048, 64, 0, stream>>>(x, wd, bd, down);
  k_enc<<<2560, 64, 0, stream>>>(down, we, be, enc);
  k_softmax<<<256, 256, 0, stream>>>(enc);
  k_zgemm<<<1024, 256, 0, stream>>>(x, wo, z);
  k_fused_out<<<4096, 256, 0, stream>>>(z, enc, bo, out);
}

// Round 4
// 198.621 us; speedup vs baseline: 1.3792x; 1.3792x over previous
//
#include <hip/hip_runtime.h>
#include <hip/hip_bf16.h>

// CARAFE: z = Wo*x at LOW res + fused reassembly (R2 structure), with
// R4: enc conv -> bf16 MFMA implicit GEMM (M=100, K=576=64ci*9tap, N=16384px).
//   - k_down outputs downT: bf16, [px][ci]-transposed, zero-padded 66x66
//     -> enc B-fragments are contiguous 16B loads; conv padding = exact zeros
//   - k_repack pre-swizzles we into A-fragment order (verified m89/m120 layout)
// N=4, H=W=64, INC=256, CM=64, KUP=5, DELTA=2, enc_out=100, OUTC=256.

namespace {
constexpr int kN = 4, kH = 64, kW = 64, kINC = 256, kCM = 64;
constexpr int kENC = 100, kH2 = 128, kW2 = 128, kOUTC = 256;
constexpr int kHW = kH * kW;       // 4096
constexpr int kHW2 = kH2 * kW2;    // 16384
constexpr int kPadW = 66;          // 64 + 1 halo each side
constexpr int kTImg = kPadW * kPadW * kCM;  // 278784 elems per image
}

typedef __attribute__((ext_vector_type(8))) short short8;   // 8 bf16 (4 VGPR)
typedef __attribute__((ext_vector_type(4))) float floatx4;  // MFMA acc

static __device__ __forceinline__ unsigned short bf16bits(float f) {
  __hip_bfloat16 h = __float2bfloat16(f);
  return *(unsigned short*)&h;
}

// ---------- kernel 1: 1x1 down conv -> downT bf16 [n][h+1][w+1][ci] ----------
// R2 structure: 1024 blocks (hg16 x cmg16 x n4), 256 thr; thread = 1 px, 4 cm.
__global__ __launch_bounds__(256) void k_down(
    const float* __restrict__ x, const float* __restrict__ wd,
    const float* __restrict__ bd, __hip_bfloat16* __restrict__ downT) {
  const int b = blockIdx.x;
  const int hg = b & 15, cmg = (b >> 4) & 15, n = b >> 8;
  const int tid = threadIdx.x;
  const int h = (hg << 2) + (tid >> 6), w = tid & 63;
  const int c0 = cmg << 2;
  const float* xb = x + (size_t)n * kINC * kHW + h * kW + w;
  const float* w0 = wd + (size_t)(c0    ) * kINC;
  const float* w1 = wd + (size_t)(c0 + 1) * kINC;
  const float* w2 = wd + (size_t)(c0 + 2) * kINC;
  const float* w3 = wd + (size_t)(c0 + 3) * kINC;
  float a0 = bd[c0], a1 = bd[c0 + 1], a2 = bd[c0 + 2], a3 = bd[c0 + 3];
#pragma unroll 8
  for (int c = 0; c < kINC; ++c) {
    const float xv = xb[(size_t)c * kHW];
    a0 += w0[c] * xv; a1 += w1[c] * xv; a2 += w2[c] * xv; a3 += w3[c] * xv;
  }
  union { unsigned short u[4]; uint2 v; } pk;
  pk.u[0] = bf16bits(a0); pk.u[1] = bf16bits(a1);
  pk.u[2] = bf16bits(a2); pk.u[3] = bf16bits(a3);
  __hip_bfloat16* dst = downT + (size_t)n * kTImg
                        + ((h + 1) * kPadW + (w + 1)) * kCM + c0;
  *(uint2*)dst = pk.v;
}

// ---------- kernel 1b: repack enc weights into A-fragment order, bf16 ----------
// Aswz[((tap*7+mt)*2+kh)*512 + lane*8 + j] = we[o=mt*16+(lane&15)]
//                                              [ci=kh*32+((lane>>4)&3)*8+j][tap]
// zero-padded for o >= 100. 64512 elements.
__global__ __launch_bounds__(256) void k_repack(
    const float* __restrict__ we, unsigned short* __restrict__ Aswz) {
  const int e = blockIdx.x * 256 + threadIdx.x;
  if (e >= 9 * 7 * 2 * 512) return;
  const int j = e & 7, lane = (e >> 3) & 63, kh = (e >> 9) & 1, tm = e >> 10;
  const int mt = tm % 7, tap = tm / 7;
  const int o = mt * 16 + (lane & 15);
  const int ci = kh * 32 + ((lane >> 4) & 3) * 8 + j;
  const float v = (o < kENC) ? we[(size_t)o * 576 + ci * 9 + tap] : 0.f;
  Aswz[e] = bf16bits(v);
}

// ---------- kernel 2: enc conv as MFMA GEMM -> enc fp32 (N,100,64,64) ----------
// Block = 4 waves = one row h; wave = 16-px tile x 2 M-tiles (32 o).
// K-loop: 9 taps x 2 ci-halves; B = downT (padded, contiguous 16B/lane).
__global__ __launch_bounds__(256) void k_encmfma(
    const __hip_bfloat16* __restrict__ downT,
    const unsigned short* __restrict__ Aswz,
    const float* __restrict__ be, float* __restrict__ enc) {
  const int b = blockIdx.x;                 // 1024: h(64) x mtp(4) x n(4)
  const int h = b & 63, mtp = (b >> 6) & 3, n = b >> 8;
  const int wave = threadIdx.x >> 6, lane = threadIdx.x & 63;
  const int w0 = wave << 4;
  const int col = lane & 15, quad = lane >> 4;
  const int mt0 = mtp * 2;
  const bool has2 = (mt0 + 1) < 7;
  const short* dT = (const short*)downT + (size_t)n * kTImg;
  floatx4 acc0 = {0.f, 0.f, 0.f, 0.f}, acc1 = {0.f, 0.f, 0.f, 0.f};
#pragma unroll
  for (int tap = 0; tap < 9; ++tap) {
    const int dh = tap / 3 - 1, dw = tap % 3 - 1;
    const int rowbase = ((h + 1 + dh) * kPadW + (w0 + col + 1 + dw)) * kCM
                        + quad * 8;
#pragma unroll
    for (int kh = 0; kh < 2; ++kh) {
      const short8 bf = *(const short8*)(dT + rowbase + kh * 32);
      const short8 a0 = *(const short8*)(
          Aswz + (((size_t)(tap * 7 + mt0) * 2 + kh) * 64 + lane) * 8);
      acc0 = __builtin_amdgcn_mfma_f32_16x16x32_bf16(a0, bf, acc0, 0, 0, 0);
      if (has2) {
        const short8 a1 = *(const short8*)(
            Aswz + (((size_t)(tap * 7 + mt0 + 1) * 2 + kh) * 64 + lane) * 8);
        acc1 = __builtin_amdgcn_mfma_f32_16x16x32_bf16(a1, bf, acc1, 0, 0, 0);
      }
    }
  }
  const int p = h * kW + w0 + col;
#pragma unroll
  for (int r = 0; r < 4; ++r) {
    const int o = mt0 * 16 + quad * 4 + r;
    if (o < kENC) enc[(size_t)(n * kENC + o) * kHW + p] = acc0[r] + be[o];
  }
  if (has2) {
#pragma unroll
    for (int r = 0; r < 4; ++r) {
      const int o = (mt0 + 1) * 16 + quad * 4 + r;
      if (o < kENC) enc[(size_t)(n * kENC + o) * kHW + p] = acc1[r] + be[o];
    }
  }
}

// ---------- kernel 3: softmax over the 25 kernel taps, in place ----------
__global__ __launch_bounds__(256) void k_softmax(float* __restrict__ buf) {
  const int b = blockIdx.x;                 // 256 blocks: hg(16) x d(4) x n(4)
  const int hg = b & 15, d = (b >> 4) & 3, n = b >> 6;
  const int tid = threadIdx.x;
  const int h = (hg << 2) + (tid >> 6), w = tid & 63;
  float* base = buf + ((size_t)n * kENC + d) * kHW + h * kW + w;
  float v[25];
  float m = -1e30f;
#pragma unroll
  for (int k = 0; k < 25; ++k) { v[k] = base[(size_t)k * 4 * kHW]; m = fmaxf(m, v[k]); }
  float s = 0.f;
#pragma unroll
  for (int k = 0; k < 25; ++k) { v[k] = __expf(v[k] - m); s += v[k]; }
  const float inv = 1.f / s;
#pragma unroll
  for (int k = 0; k < 25; ++k) base[(size_t)k * 4 * kHW] = v[k] * inv;
}

// ---------- kernel 4: z = Wo * x (1x1, 256->256 at 64x64 res), no bias ----------
__global__ __launch_bounds__(256) void k_zgemm(
    const float* __restrict__ x, const float* __restrict__ wo,
    float* __restrict__ z) {
  const int b = blockIdx.x;                 // 1024 blocks: pT(64) x oT(4) x n(4)
  const int pT = b & 63, oT = (b >> 6) & 3, n = b >> 8;
  const int p0 = pT << 6, o0 = oT << 6;
  const int tid = threadIdx.x;
  const int tx = tid & 15, ty = tid >> 4;
  __shared__ float As[16][64];              // [k][o]
  __shared__ float Bs[16][64];              // [k][p]
  const float* Ab = wo + (size_t)o0 * kINC;
  const float* Bb = x + (size_t)n * kINC * kHW + p0;
  float acc[4][4] = {};
  const int ar = tid >> 2, ac = (tid & 3) << 2;
  const int br = tid >> 4, bc = (tid & 15) << 2;
  for (int k0 = 0; k0 < kINC; k0 += 16) {
    const float4 av = *(const float4*)(Ab + (size_t)ar * kINC + k0 + ac);
    As[ac + 0][ar] = av.x; As[ac + 1][ar] = av.y;
    As[ac + 2][ar] = av.z; As[ac + 3][ar] = av.w;
    const float4 bv = *(const float4*)(Bb + (size_t)(k0 + br) * kHW + bc);
    *(float4*)(&Bs[br][bc]) = bv;
    __syncthreads();
#pragma unroll
    for (int kk = 0; kk < 16; ++kk) {
      const float a0 = As[kk][ty * 4 + 0], a1 = As[kk][ty * 4 + 1];
      const float a2 = As[kk][ty * 4 + 2], a3 = As[kk][ty * 4 + 3];
      const float b0 = Bs[kk][tx * 4 + 0], b1 = Bs[kk][tx * 4 + 1];
      const float b2 = Bs[kk][tx * 4 + 2], b3 = Bs[kk][tx * 4 + 3];
      acc[0][0] += a0 * b0; acc[0][1] += a0 * b1; acc[0][2] += a0 * b2; acc[0][3] += a0 * b3;
      acc[1][0] += a1 * b0; acc[1][1] += a1 * b1; acc[1][2] += a1 * b2; acc[1][3] += a1 * b3;
      acc[2][0] += a2 * b0; acc[2][1] += a2 * b1; acc[2][2] += a2 * b2; acc[2][3] += a2 * b3;
      acc[3][0] += a3 * b0; acc[3][1] += a3 * b1; acc[3][2] += a3 * b2; acc[3][3] += a3 * b3;
    }
    __syncthreads();
  }
#pragma unroll
  for (int i = 0; i < 4; ++i) {
    const int o = o0 + ty * 4 + i;
    *(float4*)(z + ((size_t)(n * kOUTC + o) * kHW) + p0 + tx * 4) =
        make_float4(acc[i][0], acc[i][1], acc[i][2], acc[i][3]);
  }
}

// ---------- kernel 5: fused reassembly + pixel shuffle + bias -> out ----------
__global__ __launch_bounds__(256) void k_fused_out(
    const float* __restrict__ z, const float* __restrict__ kern,
    const float* __restrict__ bo, float* __restrict__ out) {
  const int b = blockIdx.x;                 // 4096 blocks: hg(16) x og(64) x n(4)
  const int hg = b & 15, og = (b >> 4) & 63, n = b >> 10;
  const int tid = threadIdx.x;
  const int h = (hg << 2) + (tid >> 6), w = tid & 63;
  const int o0 = og << 2;
  const float* kb = kern + (size_t)n * kENC * kHW + h * kW + w;
  const float* zb = z + (size_t)(n * kOUTC + o0) * kHW;
  float acc[4][4] = {};                     // [o][d]
#pragma unroll
  for (int kh = 0; kh < 5; ++kh) {
    const int hh = h + kh - 2;
    if (hh < 0 || hh >= kH) continue;       // wave-uniform
#pragma unroll
    for (int kw = 0; kw < 5; ++kw) {
      const int ww = w + kw - 2;
      if (ww < 0 || ww >= kW) continue;
      const int k = kh * 5 + kw;
      const float kv0 = kb[(size_t)(k * 4    ) * kHW];
      const float kv1 = kb[(size_t)(k * 4 + 1) * kHW];
      const float kv2 = kb[(size_t)(k * 4 + 2) * kHW];
      const float kv3 = kb[(size_t)(k * 4 + 3) * kHW];
      const int xoff = hh * kW + ww;
#pragma unroll
      for (int u = 0; u < 4; ++u) {
        const float zv = zb[(size_t)u * kHW + xoff];
        acc[u][0] += zv * kv0; acc[u][1] += zv * kv1;
        acc[u][2] += zv * kv2; acc[u][3] += zv * kv3;
      }
    }
  }
#pragma unroll
  for (int u = 0; u < 4; ++u) {
    const float bias = bo[o0 + u];
#pragma unroll
    for (int i = 0; i < 2; ++i) {
      float* dst = out + ((size_t)(n * kOUTC + o0 + u) * kH2 + (2 * h + i)) * kW2 + 2 * w;
      *(float2*)dst = make_float2(acc[u][i * 2] + bias, acc[u][i * 2 + 1] + bias);
    }
  }
}

extern "C" void kernel_launch(void* const* d_in, const int* in_sizes, int n_in,
                              void* d_out, int out_size, void* d_ws, size_t ws_size,
                              hipStream_t stream) {
  const float* x  = (const float*)d_in[0];   // (4,256,64,64)
  const float* wd = (const float*)d_in[1];   // (64,256,1,1)
  const float* bd = (const float*)d_in[2];   // (64,)
  const float* we = (const float*)d_in[3];   // (100,64,3,3)
  const float* be = (const float*)d_in[4];   // (100,)
  const float* wo = (const float*)d_in[5];   // (256,256,1,1)
  const float* bo = (const float*)d_in[6];   // (256,)
  float* out = (float*)d_out;                // (4,256,128,128)

  // workspace layout: enc fp32 | z fp32 | downT bf16 (padded) | Aswz bf16
  float* enc = (float*)d_ws;                          // 1,638,400 f
  float* z   = enc + 1638400;                         // 4,194,304 f
  __hip_bfloat16* downT = (__hip_bfloat16*)(z + 4194304);   // 1,115,136 bf16
  unsigned short* Aswz  = (unsigned short*)(downT + (size_t)kN * kTImg); // 64,512

  hipMemsetAsync(downT, 0, (size_t)kN * kTImg * sizeof(__hip_bfloat16), stream);
  k_repack<<<252, 256, 0, stream>>>(we, Aswz);
  k_down<<<1024, 256, 0, stream>>>(x, wd, bd, downT);
  k_encmfma<<<1024, 256, 0, stream>>>(downT, Aswz, be, enc);
  k_softmax<<<256, 256, 0, stream>>>(enc);
  k_zgemm<<<1024, 256, 0, stream>>>(x, wo, z);
  k_fused_out<<<4096, 256, 0, stream>>>(z, enc, bo, out);
}

// Round 5
// 171.036 us; speedup vs baseline: 1.6017x; 1.1613x over previous
//
#include <hip/hip_runtime.h>
#include <hip/hip_bf16.h>

// CARAFE R5:
//  - k_dzmfma: fused down-conv (cm=64) + z=Wo*x (o=256) as one bf16 MFMA GEMM,
//    M=320 stacked [wd;wo], K=256, N=16384 px. B gathered per-lane from x
//    (dword, coalesced) + packed to bf16. Rows 0-63 -> downT bf16 padded;
//    rows 64-319 -> zT fp32 padded [px][o].
//  - k_encmfma unchanged (R4, verified).
//  - k_softmaxT: softmax -> kernT[px][100] (float4-friendly per-px layout).
//  - k_fused_out: o-fast lanes; per tap 1 float4 z + 1 float4 kern -> 16 FMA.
// N=4, H=W=64, INC=256, CM=64, KUP=5, DELTA=2, enc_out=100, OUTC=256.

namespace {
constexpr int kN = 4, kH = 64, kW = 64, kINC = 256, kCM = 64;
constexpr int kENC = 100, kH2 = 128, kW2 = 128, kOUTC = 256;
constexpr int kHW = kH * kW;       // 4096
constexpr int kHW2 = kH2 * kW2;    // 16384
constexpr int kPadW = 66;          // 64 + 1 halo (enc 3x3)
constexpr int kTImg = kPadW * kPadW * kCM;    // 278784 (downT per image)
constexpr int kZPad = 68;          // 64 + 2 halo (reassembly 5x5)
constexpr int kZImg = kZPad * kZPad * kOUTC;  // 1183744 (zT per image)
}

typedef __attribute__((ext_vector_type(8))) short short8;   // 8 bf16
typedef __attribute__((ext_vector_type(4))) float floatx4;  // MFMA acc

static __device__ __forceinline__ unsigned short bf16bits(float f) {
  __hip_bfloat16 h = __float2bfloat16(f);
  return *(unsigned short*)&h;
}

// ---------- repack enc weights into A-fragment order (R4, verified) ----------
__global__ __launch_bounds__(256) void k_repack(
    const float* __restrict__ we, unsigned short* __restrict__ Aswz) {
  const int e = blockIdx.x * 256 + threadIdx.x;
  if (e >= 9 * 7 * 2 * 512) return;
  const int j = e & 7, lane = (e >> 3) & 63, kh = (e >> 9) & 1, tm = e >> 10;
  const int mt = tm % 7, tap = tm / 7;
  const int o = mt * 16 + (lane & 15);
  const int ci = kh * 32 + ((lane >> 4) & 3) * 8 + j;
  const float v = (o < kENC) ? we[(size_t)o * 576 + ci * 9 + tap] : 0.f;
  Aswz[e] = bf16bits(v);
}

// ---------- repack stacked [wd;wo] into A-fragment order ----------
// Awoz[((ks*20+mt)*64+lane)*8+j] = W[mt*16+(lane&15)][ks*32+(lane>>4)*8+j]
// where W row r: r<64 -> wd[r], else wo[r-64]. 81920 elements.
__global__ __launch_bounds__(256) void k_repack_woz(
    const float* __restrict__ wd, const float* __restrict__ wo,
    unsigned short* __restrict__ Awoz) {
  const int e = blockIdx.x * 256 + threadIdx.x;
  if (e >= 8 * 20 * 512) return;
  const int j = e & 7, lane = (e >> 3) & 63;
  const int rest = e >> 9;
  const int mt = rest % 20, ks = rest / 20;
  const int r = mt * 16 + (lane & 15);
  const int k = ks * 32 + (lane >> 4) * 8 + j;
  const float v = (r < kCM) ? wd[(size_t)r * kINC + k]
                            : wo[(size_t)(r - kCM) * kINC + k];
  Awoz[e] = bf16bits(v);
}

// ---------- fused down + z GEMM: M=320, K=256, N=16384 ----------
// 1024 blocks (pt256 x n4) x 256 thr. Block = one 16-px tile; 4 waves split
// the 20 M-tiles (5 each). B gathered per kstep: 8 x dwords -> bf16 pack.
__global__ __launch_bounds__(256) void k_dzmfma(
    const float* __restrict__ x, const unsigned short* __restrict__ Awoz,
    const float* __restrict__ bd, __hip_bfloat16* __restrict__ downT,
    float* __restrict__ zT) {
  const int b = blockIdx.x;
  const int pt = b & 255, n = b >> 8;
  const int wave = threadIdx.x >> 6, lane = threadIdx.x & 63;
  const int col = lane & 15, quad = lane >> 4;
  const int px = pt * 16 + col;
  const int h = px >> 6, w = px & 63;
  const float* xb = x + (size_t)n * kINC * kHW + px;

  floatx4 acc[5];
#pragma unroll
  for (int m = 0; m < 5; ++m) acc[m] = (floatx4){0.f, 0.f, 0.f, 0.f};

#pragma unroll
  for (int ks = 0; ks < 8; ++ks) {
    float xv[8];
#pragma unroll
    for (int j = 0; j < 8; ++j)
      xv[j] = xb[(size_t)(ks * 32 + quad * 8 + j) * kHW];
    short8 bf;
#pragma unroll
    for (int j = 0; j < 8; ++j) bf[j] = (short)bf16bits(xv[j]);
#pragma unroll
    for (int m = 0; m < 5; ++m) {
      const int wtile = wave * 5 + m;
      const short8 af = *(const short8*)(
          Awoz + ((size_t)(ks * 20 + wtile) * 64 + lane) * 8);
      acc[m] = __builtin_amdgcn_mfma_f32_16x16x32_bf16(af, bf, acc[m], 0, 0, 0);
    }
  }

#pragma unroll
  for (int m = 0; m < 5; ++m) {
    const int wtile = wave * 5 + m;
    const int r0 = wtile * 16 + quad * 4;      // rows r0..r0+3, contiguous
    if (wtile < 4) {                            // down rows (cm), +bias, bf16
      union { unsigned short u[4]; uint2 v; } pk;
#pragma unroll
      for (int rr = 0; rr < 4; ++rr)
        pk.u[rr] = bf16bits(acc[m][rr] + bd[r0 + rr]);
      __hip_bfloat16* dst = downT + (size_t)n * kTImg
                            + ((h + 1) * kPadW + (w + 1)) * kCM + r0;
      *(uint2*)dst = pk.v;
    } else {                                    // z rows (o = r-64), fp32
      const int o = r0 - kCM;
      float* dst = zT + (size_t)n * kZImg
                   + ((h + 2) * kZPad + (w + 2)) * kOUTC + o;
      *(float4*)dst = make_float4(acc[m][0], acc[m][1], acc[m][2], acc[m][3]);
    }
  }
}

// ---------- enc conv as MFMA GEMM -> enc fp32 (N,100,64,64) (R4, verified) ----------
__global__ __launch_bounds__(256) void k_encmfma(
    const __hip_bfloat16* __restrict__ downT,
    const unsigned short* __restrict__ Aswz,
    const float* __restrict__ be, float* __restrict__ enc) {
  const int b = blockIdx.x;                 // 1024: h(64) x mtp(4) x n(4)
  const int h = b & 63, mtp = (b >> 6) & 3, n = b >> 8;
  const int wave = threadIdx.x >> 6, lane = threadIdx.x & 63;
  const int w0 = wave << 4;
  const int col = lane & 15, quad = lane >> 4;
  const int mt0 = mtp * 2;
  const bool has2 = (mt0 + 1) < 7;
  const short* dT = (const short*)downT + (size_t)n * kTImg;
  floatx4 acc0 = {0.f, 0.f, 0.f, 0.f}, acc1 = {0.f, 0.f, 0.f, 0.f};
#pragma unroll
  for (int tap = 0; tap < 9; ++tap) {
    const int dh = tap / 3 - 1, dw = tap % 3 - 1;
    const int rowbase = ((h + 1 + dh) * kPadW + (w0 + col + 1 + dw)) * kCM
                        + quad * 8;
#pragma unroll
    for (int kh = 0; kh < 2; ++kh) {
      const short8 bf = *(const short8*)(dT + rowbase + kh * 32);
      const short8 a0 = *(const short8*)(
          Aswz + (((size_t)(tap * 7 + mt0) * 2 + kh) * 64 + lane) * 8);
      acc0 = __builtin_amdgcn_mfma_f32_16x16x32_bf16(a0, bf, acc0, 0, 0, 0);
      if (has2) {
        const short8 a1 = *(const short8*)(
            Aswz + (((size_t)(tap * 7 + mt0 + 1) * 2 + kh) * 64 + lane) * 8);
        acc1 = __builtin_amdgcn_mfma_f32_16x16x32_bf16(a1, bf, acc1, 0, 0, 0);
      }
    }
  }
  const int p = h * kW + w0 + col;
#pragma unroll
  for (int r = 0; r < 4; ++r) {
    const int o = mt0 * 16 + quad * 4 + r;
    if (o < kENC) enc[(size_t)(n * kENC + o) * kHW + p] = acc0[r] + be[o];
  }
  if (has2) {
#pragma unroll
    for (int r = 0; r < 4; ++r) {
      const int o = (mt0 + 1) * 16 + quad * 4 + r;
      if (o < kENC) enc[(size_t)(n * kENC + o) * kHW + p] = acc1[r] + be[o];
    }
  }
}

// ---------- softmax over 25 taps -> kernT[n][px][100] ----------
// 256 blocks x 64 thr; thread = one px, all 4 subpixels.
__global__ __launch_bounds__(64) void k_softmaxT(
    const float* __restrict__ enc, float* __restrict__ kernT) {
  const int t = blockIdx.x * 64 + threadIdx.x;
  const int n = t >> 12, px = t & 4095;
  const float* base = enc + (size_t)n * kENC * kHW + px;
  float v[100];
#pragma unroll
  for (int ch = 0; ch < 100; ++ch) v[ch] = base[(size_t)ch * kHW];
  float inv[4];
#pragma unroll
  for (int d = 0; d < 4; ++d) {
    float m = -1e30f;
#pragma unroll
    for (int k = 0; k < 25; ++k) m = fmaxf(m, v[k * 4 + d]);
    float s = 0.f;
#pragma unroll
    for (int k = 0; k < 25; ++k) { v[k * 4 + d] = __expf(v[k * 4 + d] - m); s += v[k * 4 + d]; }
    inv[d] = 1.f / s;
  }
  float* dst = kernT + ((size_t)n * kHW + px) * 100;
#pragma unroll
  for (int k = 0; k < 25; ++k)
    *(float4*)(dst + k * 4) = make_float4(v[k * 4 + 0] * inv[0], v[k * 4 + 1] * inv[1],
                                          v[k * 4 + 2] * inv[2], v[k * 4 + 3] * inv[3]);
}

// ---------- fused reassembly + pixel shuffle + bias -> out ----------
// 4096 blocks: pt(256) x ob(4) x n(4); 256 thr. Lane: oc = lane&15 (4 o's),
// pxi = lane>>4; wave covers 4 px x 64 o. Per tap: 1 float4 z + 1 float4 kern
// -> 16 FMA.
__global__ __launch_bounds__(256) void k_fused_out(
    const float* __restrict__ zT, const float* __restrict__ kernT,
    const float* __restrict__ bo, float* __restrict__ out) {
  const int b = blockIdx.x;
  const int pt = b & 255, ob = (b >> 8) & 3, n = b >> 10;
  const int wave = threadIdx.x >> 6, lane = threadIdx.x & 63;
  const int oc = lane & 15, pxi = lane >> 4;
  const int px = pt * 16 + wave * 4 + pxi;
  const int h = px >> 6, w = px & 63;
  const int o = ob * 64 + oc * 4;
  const float* kb = kernT + ((size_t)n * kHW + px) * 100;
  const float* zb = zT + (size_t)n * kZImg + o;
  float acc[4][4] = {};                     // [oi][d]
#pragma unroll
  for (int tap = 0; tap < 25; ++tap) {
    const int kh = tap / 5 - 2, kw = tap % 5 - 2;
    const float4 kf = *(const float4*)(kb + tap * 4);
    const float4 zf = *(const float4*)(
        zb + ((size_t)(h + 2 + kh) * kZPad + (w + 2 + kw)) * kOUTC);
    acc[0][0] += zf.x * kf.x; acc[0][1] += zf.x * kf.y; acc[0][2] += zf.x * kf.z; acc[0][3] += zf.x * kf.w;
    acc[1][0] += zf.y * kf.x; acc[1][1] += zf.y * kf.y; acc[1][2] += zf.y * kf.z; acc[1][3] += zf.y * kf.w;
    acc[2][0] += zf.z * kf.x; acc[2][1] += zf.z * kf.y; acc[2][2] += zf.z * kf.z; acc[2][3] += zf.z * kf.w;
    acc[3][0] += zf.w * kf.x; acc[3][1] += zf.w * kf.y; acc[3][2] += zf.w * kf.z; acc[3][3] += zf.w * kf.w;
  }
#pragma unroll
  for (int oi = 0; oi < 4; ++oi) {
    const float bias = bo[o + oi];
#pragma unroll
    for (int i = 0; i < 2; ++i) {
      float* dst = out + ((size_t)(n * kOUTC + o + oi) * kH2 + (2 * h + i)) * kW2 + 2 * w;
      *(float2*)dst = make_float2(acc[oi][i * 2] + bias, acc[oi][i * 2 + 1] + bias);
    }
  }
}

extern "C" void kernel_launch(void* const* d_in, const int* in_sizes, int n_in,
                              void* d_out, int out_size, void* d_ws, size_t ws_size,
                              hipStream_t stream) {
  const float* x  = (const float*)d_in[0];   // (4,256,64,64)
  const float* wd = (const float*)d_in[1];   // (64,256,1,1)
  const float* bd = (const float*)d_in[2];   // (64,)
  const float* we = (const float*)d_in[3];   // (100,64,3,3)
  const float* be = (const float*)d_in[4];   // (100,)
  const float* wo = (const float*)d_in[5];   // (256,256,1,1)
  const float* bo = (const float*)d_in[6];   // (256,)
  float* out = (float*)d_out;                // (4,256,128,128)

  // workspace (all 16B-aligned):
  float* enc   = (float*)d_ws;                        // 1,638,400 f
  float* kernT = enc + 1638400;                       // 1,638,400 f
  float* zT    = kernT + 1638400;                     // 4,734,976 f (padded 68x68)
  __hip_bfloat16* downT = (__hip_bfloat16*)(zT + 4734976);      // 1,115,136 bf16
  unsigned short* Aswz  = (unsigned short*)(downT + (size_t)kN * kTImg); // 64,512
  unsigned short* Awoz  = Aswz + 64512;                          // 81,920

  hipMemsetAsync(downT, 0, (size_t)kN * kTImg * sizeof(__hip_bfloat16), stream);
  hipMemsetAsync(zT, 0, (size_t)kN * kZImg * sizeof(float), stream);
  k_repack<<<252, 256, 0, stream>>>(we, Aswz);
  k_repack_woz<<<320, 256, 0, stream>>>(wd, wo, Awoz);
  k_dzmfma<<<1024, 256, 0, stream>>>(x, Awoz, bd, downT, zT);
  k_encmfma<<<1024, 256, 0, stream>>>(downT, Aswz, be, enc);
  k_softmaxT<<<256, 64, 0, stream>>>(enc, kernT);
  k_fused_out<<<4096, 256, 0, stream>>>(zT, kernT, bo, out);
}

// Round 6
// 150.006 us; speedup vs baseline: 1.8262x; 1.1402x over previous
//
#include <hip/hip_runtime.h>
#include <hip/hip_bf16.h>

// CARAFE R6:
//  - k_dzmfma: fused down+z GEMM (unchanged from R5, verified).
//  - k_encmfma: enc conv MFMA GEMM (unchanged from R4, verified).
//  - k_softmax: R4 in-place softmax on enc [ch][px] (reverted; kernT deleted).
//  - k_fused_out v3: o-fast lanes (coalesced z loads), kern tile staged in LDS
//    from enc, acc transposed through LDS (stride-65 pad) -> coalesced float4
//    stores. VGPR target <=64.
//  - k_halo: clears only the zT/downT halos (was 21 MB of memset, now 2.7 MB).
// N=4, H=W=64, INC=256, CM=64, KUP=5, DELTA=2, enc_out=100, OUTC=256.

namespace {
constexpr int kN = 4, kH = 64, kW = 64, kINC = 256, kCM = 64;
constexpr int kENC = 100, kH2 = 128, kW2 = 128, kOUTC = 256;
constexpr int kHW = kH * kW;       // 4096
constexpr int kHW2 = kH2 * kW2;    // 16384
constexpr int kPadW = 66;          // 64 + 1 halo (enc 3x3)
constexpr int kTImg = kPadW * kPadW * kCM;    // 278784 (downT per image)
constexpr int kZPad = 68;          // 64 + 2 halo (reassembly 5x5)
constexpr int kZImg = kZPad * kZPad * kOUTC;  // 1183744 (zT per image)
}

typedef __attribute__((ext_vector_type(8))) short short8;   // 8 bf16
typedef __attribute__((ext_vector_type(4))) float floatx4;  // MFMA acc

static __device__ __forceinline__ unsigned short bf16bits(float f) {
  __hip_bfloat16 h = __float2bfloat16(f);
  return *(unsigned short*)&h;
}

// ---------- halo clear: zT (68x68 pad=2) + downT (66x66 pad=1) ----------
// zT halo: 528 px * 256 f = 16 float4-chunks each; downT halo: 260 px * 64 bf16
// = 8 float4-chunks each. Total threads: 4n*(528*16 + 260*8) = 42112.
__global__ __launch_bounds__(256) void k_halo(
    float* __restrict__ zT, __hip_bfloat16* __restrict__ downT) {
  const int t = blockIdx.x * 256 + threadIdx.x;
  if (t < 4 * 528 * 16) {
    const int chunk = t & 15, rest = t >> 4;
    const int i = rest % 528, n = rest / 528;
    int r, c;
    if (i < 272) { r = i / 68; if (r >= 2) r += 64; c = i % 68; }
    else { const int j = i - 272; r = 2 + (j >> 2); const int cc = j & 3; c = (cc < 2) ? cc : cc + 64; }
    float4* p = (float4*)(zT + (size_t)n * kZImg + ((size_t)r * kZPad + c) * kOUTC) + chunk;
    *p = make_float4(0.f, 0.f, 0.f, 0.f);
  } else if (t < 4 * 528 * 16 + 4 * 260 * 8) {
    const int u = t - 4 * 528 * 16;
    const int chunk = u & 7, rest = u >> 3;
    const int i = rest % 260, n = rest / 260;
    int r, c;
    if (i < 132) { r = (i / 66) ? 65 : 0; c = i % 66; }
    else { const int j = i - 132; r = 1 + (j >> 1); c = (j & 1) ? 65 : 0; }
    float4* p = (float4*)((char*)downT
                + ((size_t)n * kTImg + ((size_t)r * kPadW + c) * kCM) * 2) + chunk;
    *p = make_float4(0.f, 0.f, 0.f, 0.f);
  }
}

// ---------- repack enc weights into A-fragment order (R4, verified) ----------
__global__ __launch_bounds__(256) void k_repack(
    const float* __restrict__ we, unsigned short* __restrict__ Aswz) {
  const int e = blockIdx.x * 256 + threadIdx.x;
  if (e >= 9 * 7 * 2 * 512) return;
  const int j = e & 7, lane = (e >> 3) & 63, kh = (e >> 9) & 1, tm = e >> 10;
  const int mt = tm % 7, tap = tm / 7;
  const int o = mt * 16 + (lane & 15);
  const int ci = kh * 32 + ((lane >> 4) & 3) * 8 + j;
  const float v = (o < kENC) ? we[(size_t)o * 576 + ci * 9 + tap] : 0.f;
  Aswz[e] = bf16bits(v);
}

// ---------- repack stacked [wd;wo] into A-fragment order (R5, verified) ----------
__global__ __launch_bounds__(256) void k_repack_woz(
    const float* __restrict__ wd, const float* __restrict__ wo,
    unsigned short* __restrict__ Awoz) {
  const int e = blockIdx.x * 256 + threadIdx.x;
  if (e >= 8 * 20 * 512) return;
  const int j = e & 7, lane = (e >> 3) & 63;
  const int rest = e >> 9;
  const int mt = rest % 20, ks = rest / 20;
  const int r = mt * 16 + (lane & 15);
  const int k = ks * 32 + (lane >> 4) * 8 + j;
  const float v = (r < kCM) ? wd[(size_t)r * kINC + k]
                            : wo[(size_t)(r - kCM) * kINC + k];
  Awoz[e] = bf16bits(v);
}

// ---------- fused down + z GEMM: M=320, K=256, N=16384 (R5, verified) ----------
__global__ __launch_bounds__(256) void k_dzmfma(
    const float* __restrict__ x, const unsigned short* __restrict__ Awoz,
    const float* __restrict__ bd, __hip_bfloat16* __restrict__ downT,
    float* __restrict__ zT) {
  const int b = blockIdx.x;
  const int pt = b & 255, n = b >> 8;
  const int wave = threadIdx.x >> 6, lane = threadIdx.x & 63;
  const int col = lane & 15, quad = lane >> 4;
  const int px = pt * 16 + col;
  const int h = px >> 6, w = px & 63;
  const float* xb = x + (size_t)n * kINC * kHW + px;

  floatx4 acc[5];
#pragma unroll
  for (int m = 0; m < 5; ++m) acc[m] = (floatx4){0.f, 0.f, 0.f, 0.f};

#pragma unroll
  for (int ks = 0; ks < 8; ++ks) {
    float xv[8];
#pragma unroll
    for (int j = 0; j < 8; ++j)
      xv[j] = xb[(size_t)(ks * 32 + quad * 8 + j) * kHW];
    short8 bf;
#pragma unroll
    for (int j = 0; j < 8; ++j) bf[j] = (short)bf16bits(xv[j]);
#pragma unroll
    for (int m = 0; m < 5; ++m) {
      const int wtile = wave * 5 + m;
      const short8 af = *(const short8*)(
          Awoz + ((size_t)(ks * 20 + wtile) * 64 + lane) * 8);
      acc[m] = __builtin_amdgcn_mfma_f32_16x16x32_bf16(af, bf, acc[m], 0, 0, 0);
    }
  }

#pragma unroll
  for (int m = 0; m < 5; ++m) {
    const int wtile = wave * 5 + m;
    const int r0 = wtile * 16 + quad * 4;
    if (wtile < 4) {
      union { unsigned short u[4]; uint2 v; } pk;
#pragma unroll
      for (int rr = 0; rr < 4; ++rr)
        pk.u[rr] = bf16bits(acc[m][rr] + bd[r0 + rr]);
      __hip_bfloat16* dst = downT + (size_t)n * kTImg
                            + ((h + 1) * kPadW + (w + 1)) * kCM + r0;
      *(uint2*)dst = pk.v;
    } else {
      const int o = r0 - kCM;
      float* dst = zT + (size_t)n * kZImg
                   + ((h + 2) * kZPad + (w + 2)) * kOUTC + o;
      *(float4*)dst = make_float4(acc[m][0], acc[m][1], acc[m][2], acc[m][3]);
    }
  }
}

// ---------- enc conv as MFMA GEMM -> enc fp32 (N,100,64,64) (R4, verified) ----------
__global__ __launch_bounds__(256) void k_encmfma(
    const __hip_bfloat16* __restrict__ downT,
    const unsigned short* __restrict__ Aswz,
    const float* __restrict__ be, float* __restrict__ enc) {
  const int b = blockIdx.x;                 // 1024: h(64) x mtp(4) x n(4)
  const int h = b & 63, mtp = (b >> 6) & 3, n = b >> 8;
  const int wave = threadIdx.x >> 6, lane = threadIdx.x & 63;
  const int w0 = wave << 4;
  const int col = lane & 15, quad = lane >> 4;
  const int mt0 = mtp * 2;
  const bool has2 = (mt0 + 1) < 7;
  const short* dT = (const short*)downT + (size_t)n * kTImg;
  floatx4 acc0 = {0.f, 0.f, 0.f, 0.f}, acc1 = {0.f, 0.f, 0.f, 0.f};
#pragma unroll
  for (int tap = 0; tap < 9; ++tap) {
    const int dh = tap / 3 - 1, dw = tap % 3 - 1;
    const int rowbase = ((h + 1 + dh) * kPadW + (w0 + col + 1 + dw)) * kCM
                        + quad * 8;
#pragma unroll
    for (int kh = 0; kh < 2; ++kh) {
      const short8 bf = *(const short8*)(dT + rowbase + kh * 32);
      const short8 a0 = *(const short8*)(
          Aswz + (((size_t)(tap * 7 + mt0) * 2 + kh) * 64 + lane) * 8);
      acc0 = __builtin_amdgcn_mfma_f32_16x16x32_bf16(a0, bf, acc0, 0, 0, 0);
      if (has2) {
        const short8 a1 = *(const short8*)(
            Aswz + (((size_t)(tap * 7 + mt0 + 1) * 2 + kh) * 64 + lane) * 8);
        acc1 = __builtin_amdgcn_mfma_f32_16x16x32_bf16(a1, bf, acc1, 0, 0, 0);
      }
    }
  }
  const int p = h * kW + w0 + col;
#pragma unroll
  for (int r = 0; r < 4; ++r) {
    const int o = mt0 * 16 + quad * 4 + r;
    if (o < kENC) enc[(size_t)(n * kENC + o) * kHW + p] = acc0[r] + be[o];
  }
  if (has2) {
#pragma unroll
    for (int r = 0; r < 4; ++r) {
      const int o = (mt0 + 1) * 16 + quad * 4 + r;
      if (o < kENC) enc[(size_t)(n * kENC + o) * kHW + p] = acc1[r] + be[o];
    }
  }
}

// ---------- softmax over the 25 kernel taps, in place (R4, verified) ----------
__global__ __launch_bounds__(256) void k_softmax(float* __restrict__ buf) {
  const int b = blockIdx.x;                 // 256 blocks: hg(16) x d(4) x n(4)
  const int hg = b & 15, d = (b >> 4) & 3, n = b >> 6;
  const int tid = threadIdx.x;
  const int h = (hg << 2) + (tid >> 6), w = tid & 63;
  float* base = buf + ((size_t)n * kENC + d) * kHW + h * kW + w;
  float v[25];
  float m = -1e30f;
#pragma unroll
  for (int k = 0; k < 25; ++k) { v[k] = base[(size_t)k * 4 * kHW]; m = fmaxf(m, v[k]); }
  float s = 0.f;
#pragma unroll
  for (int k = 0; k < 25; ++k) { v[k] = __expf(v[k] - m); s += v[k]; }
  const float inv = 1.f / s;
#pragma unroll
  for (int k = 0; k < 25; ++k) base[(size_t)k * 4 * kHW] = v[k] * inv;
}

// ---------- fused reassembly + pixel shuffle + bias -> out (v3) ----------
// 4096 blocks: pt(256) x og(4) x n(4); 256 thr = 4 waves.
// Block tile: 16 px (one h row segment) x 64 o x 4 d.
// Phase 1: stage kern[16 px][100 ch] in LDS (from in-place softmaxed enc).
// Phase 2: taps: z float4 (lane-contiguous o) + kern ds_read_b128 -> 16 FMA.
// Phase 3: acc -> LDS (stride-65 pad, conflict-free) -> coalesced float4 out.
__global__ __launch_bounds__(256) void k_fused_out(
    const float* __restrict__ zT, const float* __restrict__ enc,
    const float* __restrict__ bo, float* __restrict__ out) {
  const int b = blockIdx.x;
  const int pt = b & 255, og = (b >> 8) & 3, n = b >> 10;
  const int tid = threadIdx.x;
  const int wave = tid >> 6, lane = tid & 63;
  const int h = pt >> 2, w0 = (pt & 3) << 4;   // 16-px segment [w0, w0+16)
  const int px0 = pt * 16;                     // linear px base

  __shared__ float lds[64 * 65];               // 16.6 KB; kern tile then acc^T
  float* kernLDS = lds;                        // [16 px][104] (pad 100->104)

  // --- phase 1: stage kern tile ---
  {
    const int p = tid & 15, chb = tid >> 4;
#pragma unroll
    for (int r = 0; r < 7; ++r) {
      const int ch = r * 16 + chb;
      if (ch < kENC)
        kernLDS[p * 104 + ch] = enc[((size_t)n * kENC + ch) * kHW + px0 + p];
    }
  }
  __syncthreads();

  // --- phase 2: 25 taps ---
  const int oc = lane & 15, pxi = lane >> 4;
  const int px_l = wave * 4 + pxi;             // [0,16)
  const int w = w0 + px_l;
  const int o_l = oc * 4;                      // [0,64) step 4
  const float* zb = zT + (size_t)n * kZImg + og * 64 + o_l;
  const float* kp = kernLDS + px_l * 104;
  float acc[4][4] = {};                        // [oi][d]
#pragma unroll
  for (int tap = 0; tap < 25; ++tap) {
    const int kh = tap / 5, kw = tap % 5;      // z idx: (h+2 + kh-2) = h+kh
    const float4 zf = *(const float4*)(
        zb + ((size_t)(h + kh) * kZPad + (w + kw)) * kOUTC);
    const float4 kf = *(const float4*)(kp + tap * 4);
    acc[0][0] += zf.x * kf.x; acc[0][1] += zf.x * kf.y; acc[0][2] += zf.x * kf.z; acc[0][3] += zf.x * kf.w;
    acc[1][0] += zf.y * kf.x; acc[1][1] += zf.y * kf.y; acc[1][2] += zf.y * kf.z; acc[1][3] += zf.y * kf.w;
    acc[2][0] += zf.z * kf.x; acc[2][1] += zf.z * kf.y; acc[2][2] += zf.z * kf.z; acc[2][3] += zf.z * kf.w;
    acc[3][0] += zf.w * kf.x; acc[3][1] += zf.w * kf.y; acc[3][2] += zf.w * kf.z; acc[3][3] += zf.w * kf.w;
  }

  // --- phase 3: transpose via LDS, coalesced stores ---
  __syncthreads();                             // kern tile fully consumed
#pragma unroll
  for (int oi = 0; oi < 4; ++oi)
#pragma unroll
    for (int d = 0; d < 4; ++d)
      lds[(o_l + oi) * 65 + px_l * 4 + d] = acc[oi][d];
  __syncthreads();

  const int ol2 = tid >> 2, q = tid & 3;       // thread: one o row, quarter
  const int o = og * 64 + ol2;
  const float bias = bo[o];
  const float* Trow = lds + ol2 * 65;
#pragma unroll
  for (int i = 0; i < 2; ++i) {
    float* row = out + ((size_t)(n * kOUTC + o) * kH2 + (2 * h + i)) * kW2 + 2 * w0;
#pragma unroll
    for (int s = 0; s < 2; ++s) {
      const int xb_ = s * 16 + q * 4;          // x offset in [0,32)
      float4 v;
      v.x = Trow[((xb_ + 0) >> 1) * 4 + i * 2 + ((xb_ + 0) & 1)] + bias;
      v.y = Trow[((xb_ + 1) >> 1) * 4 + i * 2 + ((xb_ + 1) & 1)] + bias;
      v.z = Trow[((xb_ + 2) >> 1) * 4 + i * 2 + ((xb_ + 2) & 1)] + bias;
      v.w = Trow[((xb_ + 3) >> 1) * 4 + i * 2 + ((xb_ + 3) & 1)] + bias;
      *(float4*)(row + xb_) = v;
    }
  }
}

extern "C" void kernel_launch(void* const* d_in, const int* in_sizes, int n_in,
                              void* d_out, int out_size, void* d_ws, size_t ws_size,
                              hipStream_t stream) {
  const float* x  = (const float*)d_in[0];   // (4,256,64,64)
  const float* wd = (const float*)d_in[1];   // (64,256,1,1)
  const float* bd = (const float*)d_in[2];   // (64,)
  const float* we = (const float*)d_in[3];   // (100,64,3,3)
  const float* be = (const float*)d_in[4];   // (100,)
  const float* wo = (const float*)d_in[5];   // (256,256,1,1)
  const float* bo = (const float*)d_in[6];   // (256,)
  float* out = (float*)d_out;                // (4,256,128,128)

  // workspace (all 16B-aligned):
  float* enc = (float*)d_ws;                          // 1,638,400 f
  float* zT  = enc + 1638400;                         // 4,734,976 f (padded 68x68)
  __hip_bfloat16* downT = (__hip_bfloat16*)(zT + 4734976);      // 1,115,136 bf16
  unsigned short* Aswz  = (unsigned short*)(downT + (size_t)kN * kTImg); // 64,512
  unsigned short* Awoz  = Aswz + 64512;                          // 81,920

  k_halo<<<165, 256, 0, stream>>>(zT, downT);
  k_repack<<<252, 256, 0, stream>>>(we, Aswz);
  k_repack_woz<<<320, 256, 0, stream>>>(wd, wo, Awoz);
  k_dzmfma<<<1024, 256, 0, stream>>>(x, Awoz, bd, downT, zT);
  k_encmfma<<<1024, 256, 0, stream>>>(downT, Aswz, be, enc);
  k_softmax<<<256, 256, 0, stream>>>(enc);
  k_fused_out<<<4096, 256, 0, stream>>>(zT, enc, bo, out);
}